// Round 4
// baseline (229.759 us; speedup 1.0000x reference)
//
#include <hip/hip_runtime.h>
#include <hip/hip_bf16.h>
#include <math.h>

// Problem constants (fixed by the reference)
#define BB   8
#define NQ   256
#define NKV  1024
#define DD   256   // DQ == DK == DV == 256
#define HH   128   // hidden
#define KSPLIT 4   // k-splits per q-tile (flash-style partial softmax)
#define KCH  256   // k per split (NKV / KSPLIT)

typedef float f16v __attribute__((ext_vector_type(16)));

// ---------------------------------------------------------------------------
// Kernel 1: fused projection + exp.
//   Eq[row][h] = exp(2 * dot(Q[row,:], Wq[h,:]))   rows 0..2047
//   Ek[row][h] = exp(2 * dot(K[row,:], Wk[h,:]))   rows 0..8191
// 16-row x 128-h tile per block, 256 threads (4 waves), grid 640 blocks.
// A-tile staged in LDS ONCE (single barrier); W streamed from L1/L2.
// Thread = 2 rows (rp, rp+8) x 4 h (hq*4..hq*4+3); acc = 2x4 f32.
// ---------------------------------------------------------------------------
__global__ __launch_bounds__(256) void proj_exp_kernel(
    const float* __restrict__ Q, const float* __restrict__ K,
    const float* __restrict__ Wq, const float* __restrict__ Wk,
    float* __restrict__ eqb, float* __restrict__ ekb)
{
    __shared__ __align__(16) float Asm[16][260];   // +4 pad: banks spread

    const int bid = blockIdx.x;
    const bool isQ = bid < (BB * NQ / 16);         // first 128 blocks: Q part
    const float* A = isQ ? Q : K;
    const float* W = isQ ? Wq : Wk;
    float* Out     = isQ ? eqb : ekb;
    const int arow0 = (isQ ? bid : bid - (BB * NQ / 16)) * 16;

    const int tid = threadIdx.x;
    const int hq  = tid & 31;    // h-quad: h = hq*4..hq*4+3
    const int rp  = tid >> 5;    // rows rp and rp+8

    // stage A tile: 16 rows x 256 cols, coalesced (wave = one full row)
#pragma unroll
    for (int i = 0; i < 4; ++i) {
        int idx = tid + i * 256;
        int row = idx >> 6;
        int col = (idx & 63) * 4;
        float4 a = *(const float4*)(A + (size_t)(arow0 + row) * DD + col);
        *(float4*)&Asm[row][col] = a;
    }
    __syncthreads();

    float4 c0 = {0.f,0.f,0.f,0.f}, c1 = c0;
    const float* wb = W + (size_t)(hq * 4) * DD;

    for (int d = 0; d < DD; d += 4) {
        float4 a0 = *(const float4*)&Asm[rp][d];
        float4 a1 = *(const float4*)&Asm[rp + 8][d];
        float4 w0 = *(const float4*)(wb + 0 * DD + d);
        float4 w1 = *(const float4*)(wb + 1 * DD + d);
        float4 w2 = *(const float4*)(wb + 2 * DD + d);
        float4 w3 = *(const float4*)(wb + 3 * DD + d);
        c0.x = fmaf(a0.x, w0.x, c0.x); c0.x = fmaf(a0.y, w0.y, c0.x);
        c0.x = fmaf(a0.z, w0.z, c0.x); c0.x = fmaf(a0.w, w0.w, c0.x);
        c0.y = fmaf(a0.x, w1.x, c0.y); c0.y = fmaf(a0.y, w1.y, c0.y);
        c0.y = fmaf(a0.z, w1.z, c0.y); c0.y = fmaf(a0.w, w1.w, c0.y);
        c0.z = fmaf(a0.x, w2.x, c0.z); c0.z = fmaf(a0.y, w2.y, c0.z);
        c0.z = fmaf(a0.z, w2.z, c0.z); c0.z = fmaf(a0.w, w2.w, c0.z);
        c0.w = fmaf(a0.x, w3.x, c0.w); c0.w = fmaf(a0.y, w3.y, c0.w);
        c0.w = fmaf(a0.z, w3.z, c0.w); c0.w = fmaf(a0.w, w3.w, c0.w);
        c1.x = fmaf(a1.x, w0.x, c1.x); c1.x = fmaf(a1.y, w0.y, c1.x);
        c1.x = fmaf(a1.z, w0.z, c1.x); c1.x = fmaf(a1.w, w0.w, c1.x);
        c1.y = fmaf(a1.x, w1.x, c1.y); c1.y = fmaf(a1.y, w1.y, c1.y);
        c1.y = fmaf(a1.z, w1.z, c1.y); c1.y = fmaf(a1.w, w1.w, c1.y);
        c1.z = fmaf(a1.x, w2.x, c1.z); c1.z = fmaf(a1.y, w2.y, c1.z);
        c1.z = fmaf(a1.z, w2.z, c1.z); c1.z = fmaf(a1.w, w2.w, c1.z);
        c1.w = fmaf(a1.x, w3.x, c1.w); c1.w = fmaf(a1.y, w3.y, c1.w);
        c1.w = fmaf(a1.z, w3.z, c1.w); c1.w = fmaf(a1.w, w3.w, c1.w);
    }

    float4 o;
    float* p0 = Out + (size_t)(arow0 + rp) * HH + hq * 4;
    o.x = __expf(2.f*c0.x); o.y = __expf(2.f*c0.y);
    o.z = __expf(2.f*c0.z); o.w = __expf(2.f*c0.w);
    *(float4*)p0 = o;
    float* p1 = Out + (size_t)(arow0 + rp + 8) * HH + hq * 4;
    o.x = __expf(2.f*c1.x); o.y = __expf(2.f*c1.y);
    o.z = __expf(2.f*c1.z); o.w = __expf(2.f*c1.w);
    *(float4*)p1 = o;
}

// ---------------------------------------------------------------------------
// Kernel 2: flash-style partial attention over a 256-wide k-slice.
// Grid: B*(NQ/8)*KSPLIT = 1024 blocks, 512 threads (8 waves).
// Score phase (verified math): Wv[h]*tanh(q+k) = Wv[h] - 2*Wv[h]*rcp(1+Eq*Ek).
// PV phase v3: wave w owns k-slice [w*32, w*32+32), accumulates ALL 8 rows
// in registers (V row read ONCE per block, 8x less L2/L3 traffic than v2);
// 2-stage LDS tree reduction; then per-slice (m,l) + unnormalized PV -> ws.
// ---------------------------------------------------------------------------
__global__ __launch_bounds__(512) void attn_partial_kernel(
    const float* __restrict__ V, const int* __restrict__ vls,
    const float* __restrict__ Wv,
    const float* __restrict__ eqb, const float* __restrict__ ekb,
    float* __restrict__ pvb, float* __restrict__ mlb)
{
    __shared__ __align__(16) float sc[8][KCH];        // scores then P (8 KB)
    __shared__ __align__(16) float red[4][8][KCH];    // PV partials (32 KB)

    const int bid  = blockIdx.x;
    const int s    = bid & (KSPLIT - 1);
    const int t    = bid >> 2;          // q-tile 0..255
    const int b    = t >> 5;
    const int k0   = s << 8;            // slice base
    const int r0   = t * 8;             // global row base = b*NQ + q0
    const int tid  = threadIdx.x;
    const int w    = tid >> 6;          // wave 0..7
    const int lane = tid & 63;
    const int vl   = vls[b];

    if (k0 >= vl) {
        // fully-masked slice: zero partial PV, ml = (-1e30, 0), retire.
        float4 z = {0.f, 0.f, 0.f, 0.f};
        ((float4*)(pvb + ((size_t)(r0 + w) * KSPLIT + s) * KCH))[lane] = z;
        if (lane == 0) {
            mlb[((r0 + w) * KSPLIT + s) * 2 + 0] = -1e30f;
            mlb[((r0 + w) * KSPLIT + s) * 2 + 1] = 0.f;
        }
        return;
    }

    const int qg = w & 1;                            // q-group (rows qg*4..+3)
    const int ks = ((w >> 1) << 3) + (lane >> 3);    // 0..31 k-slot
    const int hg = lane & 7;                         // h-group (h = hg*16..+15)

    const int kcnt = min(vl - k0, KCH);              // valid k in this slice
    const int nst  = (kcnt + 31) >> 5;               // 1..8 k-steps

    // Wv slice: nw2[j] = -2*Wv[hg*16+j]; swv = sum of own Wv (acc init)
    f16v nw2;
    float swv = 0.f;
#pragma unroll
    for (int i = 0; i < 4; ++i) {
        float4 v4 = *(const float4*)(Wv + hg * 16 + i * 4);
        nw2[i*4+0] = -2.f * v4.x; nw2[i*4+1] = -2.f * v4.y;
        nw2[i*4+2] = -2.f * v4.z; nw2[i*4+3] = -2.f * v4.w;
        swv += v4.x + v4.y + v4.z + v4.w;
    }

    // Eq rows in registers: 4 rows x 16 h
    f16v eqr[4];
#pragma unroll
    for (int r = 0; r < 4; ++r) {
        const float4* p = (const float4*)(eqb + (size_t)(r0 + qg*4 + r) * HH + hg * 16);
        float4 x0 = p[0], x1 = p[1], x2 = p[2], x3 = p[3];
        f16v e;
        e[0]=x0.x;e[1]=x0.y;e[2]=x0.z;e[3]=x0.w; e[4]=x1.x;e[5]=x1.y;e[6]=x1.z;e[7]=x1.w;
        e[8]=x2.x;e[9]=x2.y;e[10]=x2.z;e[11]=x2.w; e[12]=x3.x;e[13]=x3.y;e[14]=x3.z;e[15]=x3.w;
        eqr[r] = e;
    }

    const float* ekbase = ekb + ((size_t)(b * NKV) + k0) * HH + hg * 16;

    auto loadEk = [&](f16v& e, int step) {
        const float4* p = (const float4*)(ekbase + (size_t)(step * 32 + ks) * HH);
        float4 x0 = p[0], x1 = p[1], x2 = p[2], x3 = p[3];
        e[0]=x0.x;e[1]=x0.y;e[2]=x0.z;e[3]=x0.w; e[4]=x1.x;e[5]=x1.y;e[6]=x1.z;e[7]=x1.w;
        e[8]=x2.x;e[9]=x2.y;e[10]=x2.z;e[11]=x2.w; e[12]=x3.x;e[13]=x3.y;e[14]=x3.z;e[15]=x3.w;
    };

    auto body = [&](const f16v& e, int step) {
        float a0 = swv, a1 = swv, a2 = swv, a3 = swv;
#pragma unroll
        for (int j = 0; j < 16; ++j) {
            float ej = e[j];
            float t0 = fmaf(eqr[0][j], ej, 1.0f);
            float t1 = fmaf(eqr[1][j], ej, 1.0f);
            float t2 = fmaf(eqr[2][j], ej, 1.0f);
            float t3 = fmaf(eqr[3][j], ej, 1.0f);
            float r0v = __builtin_amdgcn_rcpf(t0);
            float r1v = __builtin_amdgcn_rcpf(t1);
            float r2v = __builtin_amdgcn_rcpf(t2);
            float r3v = __builtin_amdgcn_rcpf(t3);
            float nj = nw2[j];
            a0 = fmaf(nj, r0v, a0);
            a1 = fmaf(nj, r1v, a1);
            a2 = fmaf(nj, r2v, a2);
            a3 = fmaf(nj, r3v, a3);
        }
        a0 += __shfl_xor(a0, 1); a0 += __shfl_xor(a0, 2); a0 += __shfl_xor(a0, 4);
        a1 += __shfl_xor(a1, 1); a1 += __shfl_xor(a1, 2); a1 += __shfl_xor(a1, 4);
        a2 += __shfl_xor(a2, 1); a2 += __shfl_xor(a2, 2); a2 += __shfl_xor(a2, 4);
        a3 += __shfl_xor(a3, 1); a3 += __shfl_xor(a3, 2); a3 += __shfl_xor(a3, 4);
        if (hg == 0) {
            int kk = step * 32 + ks;
            sc[qg*4+0][kk] = a0;
            sc[qg*4+1][kk] = a1;
            sc[qg*4+2][kk] = a2;
            sc[qg*4+3][kk] = a3;
        }
    };

    // ---- score phase over this slice (2-deep register double-buffer)
    f16v ekA, ekB;
    loadEk(ekA, 0);
    for (int st = 0; st < nst; st += 2) {
        if (st + 1 < nst) loadEk(ekB, st + 1);
        body(ekA, st);
        if (st + 1 < nst) {
            if (st + 2 < nst) loadEk(ekA, st + 2);
            body(ekB, st + 1);
        }
    }
    __syncthreads();

    // ---- per-slice masked softmax: wave w owns row w; zeroes invalid slots
    {
        float m = -1e30f;
        float sv[4];
#pragma unroll
        for (int i = 0; i < 4; ++i) {
            int kk = i * 64 + lane;
            float sval = sc[w][kk];
            sv[i] = sval;
            if (k0 + kk < vl) m = fmaxf(m, sval);
        }
#pragma unroll
        for (int off = 1; off < 64; off <<= 1) m = fmaxf(m, __shfl_xor(m, off));
        float sum = 0.f;
#pragma unroll
        for (int i = 0; i < 4; ++i) {
            int kk = i * 64 + lane;
            float p = (k0 + kk < vl) ? __expf(sv[i] - m) : 0.f;
            sum += p;
            sc[w][kk] = p;
        }
#pragma unroll
        for (int off = 1; off < 64; off <<= 1) sum += __shfl_xor(sum, off);
        if (lane == 0) {
            mlb[((r0 + w) * KSPLIT + s) * 2 + 0] = m;
            mlb[((r0 + w) * KSPLIT + s) * 2 + 1] = sum;
        }
    }
    __syncthreads();

    // ---- PV v3: wave w owns k in [w*32, w*32+32); accumulates ALL 8 rows.
    // Each V row is read exactly once per block. P broadcast from LDS.
    float4 acc[8];
#pragma unroll
    for (int r = 0; r < 8; ++r) acc[r] = make_float4(0.f, 0.f, 0.f, 0.f);
    {
        const int kbase = w * 32;
        if (kbase < kcnt) {
            const float* vb = V + ((size_t)b * NKV + k0 + kbase) * DD + lane * 4;
            for (int kk = 0; kk < 32; kk += 4) {
                float4 pr[8];
#pragma unroll
                for (int r = 0; r < 8; ++r)
                    pr[r] = *(const float4*)&sc[r][kbase + kk];   // wave-uniform
#pragma unroll
                for (int u = 0; u < 4; ++u) {
                    float4 vv = *(const float4*)(vb + (size_t)(kk + u) * DD);
#pragma unroll
                    for (int r = 0; r < 8; ++r) {
                        float p = (u == 0) ? pr[r].x : (u == 1) ? pr[r].y
                                : (u == 2) ? pr[r].z : pr[r].w;
                        acc[r].x = fmaf(p, vv.x, acc[r].x);
                        acc[r].y = fmaf(p, vv.y, acc[r].y);
                        acc[r].z = fmaf(p, vv.z, acc[r].z);
                        acc[r].w = fmaf(p, vv.w, acc[r].w);
                    }
                }
            }
        }
    }
    // 2-stage cross-wave reduction in LDS (4 + 4 waves), then row-store
    if (w < 4) {
#pragma unroll
        for (int r = 0; r < 8; ++r)
            *(float4*)&red[w][r][lane * 4] = acc[r];
    }
    __syncthreads();
    if (w >= 4) {
#pragma unroll
        for (int r = 0; r < 8; ++r) {
            float4 tv = *(const float4*)&red[w - 4][r][lane * 4];
            tv.x += acc[r].x; tv.y += acc[r].y;
            tv.z += acc[r].z; tv.w += acc[r].w;
            *(float4*)&red[w - 4][r][lane * 4] = tv;
        }
    }
    __syncthreads();
    {
        float4 o = {0.f, 0.f, 0.f, 0.f};
#pragma unroll
        for (int ss = 0; ss < 4; ++ss) {
            float4 tv = *(const float4*)&red[ss][w][lane * 4];
            o.x += tv.x; o.y += tv.y; o.z += tv.z; o.w += tv.w;
        }
        ((float4*)(pvb + ((size_t)(r0 + w) * KSPLIT + s) * KCH))[lane] = o;
    }
}

// ---------------------------------------------------------------------------
// Kernel 3: flash merge of KSPLIT partials per q-row.
// out[r][c] = sum_s exp(m_s - M) * pv[r][s][c] / (sum_s l_s * exp(m_s - M))
// Grid 512 blocks x 256 threads (4 rows per block, lane owns 4 cols).
// ---------------------------------------------------------------------------
__global__ __launch_bounds__(256) void combine_kernel(
    const float* __restrict__ pvb, const float* __restrict__ mlb,
    float* __restrict__ out)
{
    const int tid  = threadIdx.x;
    const int r    = blockIdx.x * 4 + (tid >> 6);
    const int lane = tid & 63;

    float mv[KSPLIT], lv[KSPLIT];
#pragma unroll
    for (int s = 0; s < KSPLIT; ++s) {
        mv[s] = mlb[(r * KSPLIT + s) * 2 + 0];
        lv[s] = mlb[(r * KSPLIT + s) * 2 + 1];
    }
    float M = fmaxf(fmaxf(mv[0], mv[1]), fmaxf(mv[2], mv[3]));
    float coef[KSPLIT];
    float L = 0.f;
#pragma unroll
    for (int s = 0; s < KSPLIT; ++s) {
        coef[s] = __expf(mv[s] - M);
        L = fmaf(lv[s], coef[s], L);
    }
    float rinv = 1.0f / L;

    float4 acc = {0.f, 0.f, 0.f, 0.f};
#pragma unroll
    for (int s = 0; s < KSPLIT; ++s) {
        float4 pv = ((const float4*)(pvb + ((size_t)r * KSPLIT + s) * KCH))[lane];
        float cs = coef[s];
        acc.x = fmaf(cs, pv.x, acc.x);
        acc.y = fmaf(cs, pv.y, acc.y);
        acc.z = fmaf(cs, pv.z, acc.z);
        acc.w = fmaf(cs, pv.w, acc.w);
    }
    acc.x *= rinv; acc.y *= rinv; acc.z *= rinv; acc.w *= rinv;
    *(float4*)(out + (size_t)r * DD + lane * 4) = acc;
}

// ---------------------------------------------------------------------------
extern "C" void kernel_launch(void* const* d_in, const int* in_sizes, int n_in,
                              void* d_out, int out_size, void* d_ws, size_t ws_size,
                              hipStream_t stream) {
    const float* Q   = (const float*)d_in[0];
    const float* K   = (const float*)d_in[1];
    const float* V   = (const float*)d_in[2];
    const int*   vls = (const int*)  d_in[3];
    const float* Wq  = (const float*)d_in[4];
    const float* Wk  = (const float*)d_in[5];
    const float* Wv  = (const float*)d_in[6];
    float* out = (float*)d_out;

    // ws layout: Eq 1 MB | Ek 4 MB | pv 8 MB | ml 64 KB  (total ~13.1 MB)
    float* eq = (float*)d_ws;
    float* ek = eq + (size_t)BB * NQ * HH;
    float* pv = ek + (size_t)BB * NKV * HH;
    float* ml = pv + (size_t)BB * NQ * KSPLIT * KCH;

    proj_exp_kernel<<<(BB*NQ + BB*NKV) / 16, 256, 0, stream>>>(Q, K, Wq, Wk, eq, ek);
    attn_partial_kernel<<<BB * (NQ / 8) * KSPLIT, 512, 0, stream>>>(V, vls, Wv, eq, ek, pv, ml);
    combine_kernel<<<BB * NQ / 4, 256, 0, stream>>>(pv, ml, out);
}

// Round 6
// 163.562 us; speedup vs baseline: 1.4047x; 1.4047x over previous
//
#include <hip/hip_runtime.h>
#include <hip/hip_bf16.h>
#include <math.h>

// Problem constants (fixed by the reference)
#define BB   8
#define NQ   256
#define NKV  1024
#define DD   256   // DQ == DK == DV == 256
#define HH   128   // hidden
#define KSPLIT 4   // k-splits per q-tile (flash-style partial softmax)
#define KCH  256   // k per split (NKV / KSPLIT)

typedef float f16v __attribute__((ext_vector_type(16)));

// ---------------------------------------------------------------------------
// Kernel 1: fused projection + exp.
//   Eq[row][h] = exp(2 * dot(Q[row,:], Wq[h,:]))   rows 0..2047
//   Ek[row][h] = exp(2 * dot(K[row,:], Wk[h,:]))   rows 0..8191
// v3: round-2 LDS-tiled structure (conflict-free compute reads, coalesced
// global reads) + REGISTER PREFETCH double-buffer: chunk t+1's global loads
// issue right after staging, hiding L2 latency under chunk t's 512-cy FMA
// block (round-4's 4KB-strided W streaming was the 91us latency disease).
// 16-row x 128-h tile, 8 chunks of 32 d, 256 threads, LDS 19.5 KB, grid 640.
// Thread = 2 rows (rc, rc+8) x 4 h (hc*4..hc*4+3).
// ---------------------------------------------------------------------------
__global__ __launch_bounds__(256) void proj_exp_kernel(
    const float* __restrict__ Q, const float* __restrict__ K,
    const float* __restrict__ Wq, const float* __restrict__ Wk,
    float* __restrict__ eqb, float* __restrict__ ekb)
{
    __shared__ __align__(16) float At[32][20];   // [d][row], 16 rows used
    __shared__ __align__(16) float Wt[32][132];  // [d][h], pad to 132

    const int bid = blockIdx.x;
    const bool isQ = bid < (BB * NQ / 16);       // first 128 blocks: Q part
    const float* A = isQ ? Q : K;
    const float* W = isQ ? Wq : Wk;
    float* Out     = isQ ? eqb : ekb;
    const int arow0 = (isQ ? bid : bid - (BB * NQ / 16)) * 16;

    const int tid = threadIdx.x;
    const int rc  = tid >> 5;    // rows rc and rc+8
    const int hc  = tid & 31;    // h-quad: h = hc*4..hc*4+3

    float4 c0 = {0.f,0.f,0.f,0.f}, c1 = c0;

    // register prefetch buffers for the NEXT chunk's global data
    float4 a4;       // threads 0..127: A[arow0 + tid>>3][dc + (tid&7)*4]
    float4 w4[4];    // W rows, coalesced: idx=tid+t*256 -> h=idx>>3, dw=idx&7

    // prologue: issue chunk 0 loads
    if (tid < 128)
        a4 = *(const float4*)(A + (size_t)(arow0 + (tid >> 3)) * DD + (tid & 7) * 4);
#pragma unroll
    for (int t = 0; t < 4; ++t) {
        int idx = tid + t * 256;
        int h = idx >> 3, dw = idx & 7;
        w4[t] = *(const float4*)(W + (size_t)h * DD + dw * 4);
    }

    for (int ch = 0; ch < 8; ++ch) {
        __syncthreads();   // prior chunk's LDS reads complete
        if (tid < 128) {
            int r_st = tid >> 3, dq = tid & 7;
            At[dq*4+0][r_st] = a4.x;
            At[dq*4+1][r_st] = a4.y;
            At[dq*4+2][r_st] = a4.z;
            At[dq*4+3][r_st] = a4.w;
        }
#pragma unroll
        for (int t = 0; t < 4; ++t) {
            int idx = tid + t * 256;
            int h = idx >> 3, dw = idx & 7;
            Wt[dw*4+0][h] = w4[t].x;
            Wt[dw*4+1][h] = w4[t].y;
            Wt[dw*4+2][h] = w4[t].z;
            Wt[dw*4+3][h] = w4[t].w;
        }
        __syncthreads();
        if (ch + 1 < 8) {
            // prefetch chunk ch+1: latency hides under the 32-d FMA block
            const int dc = (ch + 1) * 32;
            if (tid < 128)
                a4 = *(const float4*)(A + (size_t)(arow0 + (tid >> 3)) * DD + dc + (tid & 7) * 4);
#pragma unroll
            for (int t = 0; t < 4; ++t) {
                int idx = tid + t * 256;
                int h = idx >> 3, dw = idx & 7;
                w4[t] = *(const float4*)(W + (size_t)h * DD + dc + dw * 4);
            }
        }
#pragma unroll
        for (int d = 0; d < 32; ++d) {
            float a0  = At[d][rc];          // half-wave broadcast: free
            float a1  = At[d][rc + 8];
            float4 wv = *(const float4*)&Wt[d][hc * 4];   // contiguous: free
            c0.x = fmaf(a0, wv.x, c0.x); c0.y = fmaf(a0, wv.y, c0.y);
            c0.z = fmaf(a0, wv.z, c0.z); c0.w = fmaf(a0, wv.w, c0.w);
            c1.x = fmaf(a1, wv.x, c1.x); c1.y = fmaf(a1, wv.y, c1.y);
            c1.z = fmaf(a1, wv.z, c1.z); c1.w = fmaf(a1, wv.w, c1.w);
        }
    }

    float4 o;
    float* p0 = Out + (size_t)(arow0 + rc) * HH + hc * 4;
    o.x = __expf(2.f*c0.x); o.y = __expf(2.f*c0.y);
    o.z = __expf(2.f*c0.z); o.w = __expf(2.f*c0.w);
    *(float4*)p0 = o;
    float* p1 = Out + (size_t)(arow0 + rc + 8) * HH + hc * 4;
    o.x = __expf(2.f*c1.x); o.y = __expf(2.f*c1.y);
    o.z = __expf(2.f*c1.z); o.w = __expf(2.f*c1.w);
    *(float4*)p1 = o;
}

// ---------------------------------------------------------------------------
// Kernel 2: flash-style partial attention over a 256-wide k-slice.
// Grid: B*(NQ/8)*KSPLIT = 1024 blocks, 512 threads (8 waves).
// Score phase (verified math): Wv[h]*tanh(q+k) = Wv[h] - 2*Wv[h]*rcp(1+Eq*Ek).
// PV phase v3: wave w owns k-slice [w*32, w*32+32), accumulates ALL 8 rows
// in registers (V row read ONCE per block); 2-stage LDS tree reduction;
// then per-slice (m,l) + unnormalized PV -> ws.  (unchanged from round 4)
// ---------------------------------------------------------------------------
__global__ __launch_bounds__(512) void attn_partial_kernel(
    const float* __restrict__ V, const int* __restrict__ vls,
    const float* __restrict__ Wv,
    const float* __restrict__ eqb, const float* __restrict__ ekb,
    float* __restrict__ pvb, float* __restrict__ mlb)
{
    __shared__ __align__(16) float sc[8][KCH];        // scores then P (8 KB)
    __shared__ __align__(16) float red[4][8][KCH];    // PV partials (32 KB)

    const int bid  = blockIdx.x;
    const int s    = bid & (KSPLIT - 1);
    const int t    = bid >> 2;          // q-tile 0..255
    const int b    = t >> 5;
    const int k0   = s << 8;            // slice base
    const int r0   = t * 8;             // global row base = b*NQ + q0
    const int tid  = threadIdx.x;
    const int w    = tid >> 6;          // wave 0..7
    const int lane = tid & 63;
    const int vl   = vls[b];

    if (k0 >= vl) {
        // fully-masked slice: zero partial PV, ml = (-1e30, 0), retire.
        float4 z = {0.f, 0.f, 0.f, 0.f};
        ((float4*)(pvb + ((size_t)(r0 + w) * KSPLIT + s) * KCH))[lane] = z;
        if (lane == 0) {
            mlb[((r0 + w) * KSPLIT + s) * 2 + 0] = -1e30f;
            mlb[((r0 + w) * KSPLIT + s) * 2 + 1] = 0.f;
        }
        return;
    }

    const int qg = w & 1;                            // q-group (rows qg*4..+3)
    const int ks = ((w >> 1) << 3) + (lane >> 3);    // 0..31 k-slot
    const int hg = lane & 7;                         // h-group (h = hg*16..+15)

    const int kcnt = min(vl - k0, KCH);              // valid k in this slice
    const int nst  = (kcnt + 31) >> 5;               // 1..8 k-steps

    // Wv slice: nw2[j] = -2*Wv[hg*16+j]; swv = sum of own Wv (acc init)
    f16v nw2;
    float swv = 0.f;
#pragma unroll
    for (int i = 0; i < 4; ++i) {
        float4 v4 = *(const float4*)(Wv + hg * 16 + i * 4);
        nw2[i*4+0] = -2.f * v4.x; nw2[i*4+1] = -2.f * v4.y;
        nw2[i*4+2] = -2.f * v4.z; nw2[i*4+3] = -2.f * v4.w;
        swv += v4.x + v4.y + v4.z + v4.w;
    }

    // Eq rows in registers: 4 rows x 16 h
    f16v eqr[4];
#pragma unroll
    for (int r = 0; r < 4; ++r) {
        const float4* p = (const float4*)(eqb + (size_t)(r0 + qg*4 + r) * HH + hg * 16);
        float4 x0 = p[0], x1 = p[1], x2 = p[2], x3 = p[3];
        f16v e;
        e[0]=x0.x;e[1]=x0.y;e[2]=x0.z;e[3]=x0.w; e[4]=x1.x;e[5]=x1.y;e[6]=x1.z;e[7]=x1.w;
        e[8]=x2.x;e[9]=x2.y;e[10]=x2.z;e[11]=x2.w; e[12]=x3.x;e[13]=x3.y;e[14]=x3.z;e[15]=x3.w;
        eqr[r] = e;
    }

    const float* ekbase = ekb + ((size_t)(b * NKV) + k0) * HH + hg * 16;

    auto loadEk = [&](f16v& e, int step) {
        const float4* p = (const float4*)(ekbase + (size_t)(step * 32 + ks) * HH);
        float4 x0 = p[0], x1 = p[1], x2 = p[2], x3 = p[3];
        e[0]=x0.x;e[1]=x0.y;e[2]=x0.z;e[3]=x0.w; e[4]=x1.x;e[5]=x1.y;e[6]=x1.z;e[7]=x1.w;
        e[8]=x2.x;e[9]=x2.y;e[10]=x2.z;e[11]=x2.w; e[12]=x3.x;e[13]=x3.y;e[14]=x3.z;e[15]=x3.w;
    };

    auto body = [&](const f16v& e, int step) {
        float a0 = swv, a1 = swv, a2 = swv, a3 = swv;
#pragma unroll
        for (int j = 0; j < 16; ++j) {
            float ej = e[j];
            float t0 = fmaf(eqr[0][j], ej, 1.0f);
            float t1 = fmaf(eqr[1][j], ej, 1.0f);
            float t2 = fmaf(eqr[2][j], ej, 1.0f);
            float t3 = fmaf(eqr[3][j], ej, 1.0f);
            float r0v = __builtin_amdgcn_rcpf(t0);
            float r1v = __builtin_amdgcn_rcpf(t1);
            float r2v = __builtin_amdgcn_rcpf(t2);
            float r3v = __builtin_amdgcn_rcpf(t3);
            float nj = nw2[j];
            a0 = fmaf(nj, r0v, a0);
            a1 = fmaf(nj, r1v, a1);
            a2 = fmaf(nj, r2v, a2);
            a3 = fmaf(nj, r3v, a3);
        }
        a0 += __shfl_xor(a0, 1); a0 += __shfl_xor(a0, 2); a0 += __shfl_xor(a0, 4);
        a1 += __shfl_xor(a1, 1); a1 += __shfl_xor(a1, 2); a1 += __shfl_xor(a1, 4);
        a2 += __shfl_xor(a2, 1); a2 += __shfl_xor(a2, 2); a2 += __shfl_xor(a2, 4);
        a3 += __shfl_xor(a3, 1); a3 += __shfl_xor(a3, 2); a3 += __shfl_xor(a3, 4);
        if (hg == 0) {
            int kk = step * 32 + ks;
            sc[qg*4+0][kk] = a0;
            sc[qg*4+1][kk] = a1;
            sc[qg*4+2][kk] = a2;
            sc[qg*4+3][kk] = a3;
        }
    };

    // ---- score phase over this slice (2-deep register double-buffer)
    f16v ekA, ekB;
    loadEk(ekA, 0);
    for (int st = 0; st < nst; st += 2) {
        if (st + 1 < nst) loadEk(ekB, st + 1);
        body(ekA, st);
        if (st + 1 < nst) {
            if (st + 2 < nst) loadEk(ekA, st + 2);
            body(ekB, st + 1);
        }
    }
    __syncthreads();

    // ---- per-slice masked softmax: wave w owns row w; zeroes invalid slots
    {
        float m = -1e30f;
        float sv[4];
#pragma unroll
        for (int i = 0; i < 4; ++i) {
            int kk = i * 64 + lane;
            float sval = sc[w][kk];
            sv[i] = sval;
            if (k0 + kk < vl) m = fmaxf(m, sval);
        }
#pragma unroll
        for (int off = 1; off < 64; off <<= 1) m = fmaxf(m, __shfl_xor(m, off));
        float sum = 0.f;
#pragma unroll
        for (int i = 0; i < 4; ++i) {
            int kk = i * 64 + lane;
            float p = (k0 + kk < vl) ? __expf(sv[i] - m) : 0.f;
            sum += p;
            sc[w][kk] = p;
        }
#pragma unroll
        for (int off = 1; off < 64; off <<= 1) sum += __shfl_xor(sum, off);
        if (lane == 0) {
            mlb[((r0 + w) * KSPLIT + s) * 2 + 0] = m;
            mlb[((r0 + w) * KSPLIT + s) * 2 + 1] = sum;
        }
    }
    __syncthreads();

    // ---- PV v3: wave w owns k in [w*32, w*32+32); accumulates ALL 8 rows.
    // Each V row is read exactly once per block. P broadcast from LDS.
    float4 acc[8];
#pragma unroll
    for (int r = 0; r < 8; ++r) acc[r] = make_float4(0.f, 0.f, 0.f, 0.f);
    {
        const int kbase = w * 32;
        if (kbase < kcnt) {
            const float* vb = V + ((size_t)b * NKV + k0 + kbase) * DD + lane * 4;
            for (int kk = 0; kk < 32; kk += 4) {
                float4 pr[8];
#pragma unroll
                for (int r = 0; r < 8; ++r)
                    pr[r] = *(const float4*)&sc[r][kbase + kk];   // wave-uniform
#pragma unroll
                for (int u = 0; u < 4; ++u) {
                    float4 vv = *(const float4*)(vb + (size_t)(kk + u) * DD);
#pragma unroll
                    for (int r = 0; r < 8; ++r) {
                        float p = (u == 0) ? pr[r].x : (u == 1) ? pr[r].y
                                : (u == 2) ? pr[r].z : pr[r].w;
                        acc[r].x = fmaf(p, vv.x, acc[r].x);
                        acc[r].y = fmaf(p, vv.y, acc[r].y);
                        acc[r].z = fmaf(p, vv.z, acc[r].z);
                        acc[r].w = fmaf(p, vv.w, acc[r].w);
                    }
                }
            }
        }
    }
    // 2-stage cross-wave reduction in LDS (4 + 4 waves), then row-store
    if (w < 4) {
#pragma unroll
        for (int r = 0; r < 8; ++r)
            *(float4*)&red[w][r][lane * 4] = acc[r];
    }
    __syncthreads();
    if (w >= 4) {
#pragma unroll
        for (int r = 0; r < 8; ++r) {
            float4 tv = *(const float4*)&red[w - 4][r][lane * 4];
            tv.x += acc[r].x; tv.y += acc[r].y;
            tv.z += acc[r].z; tv.w += acc[r].w;
            *(float4*)&red[w - 4][r][lane * 4] = tv;
        }
    }
    __syncthreads();
    {
        float4 o = {0.f, 0.f, 0.f, 0.f};
#pragma unroll
        for (int ss = 0; ss < 4; ++ss) {
            float4 tv = *(const float4*)&red[ss][w][lane * 4];
            o.x += tv.x; o.y += tv.y; o.z += tv.z; o.w += tv.w;
        }
        ((float4*)(pvb + ((size_t)(r0 + w) * KSPLIT + s) * KCH))[lane] = o;
    }
}

// ---------------------------------------------------------------------------
// Kernel 3: flash merge of KSPLIT partials per q-row.  (unchanged)
// ---------------------------------------------------------------------------
__global__ __launch_bounds__(256) void combine_kernel(
    const float* __restrict__ pvb, const float* __restrict__ mlb,
    float* __restrict__ out)
{
    const int tid  = threadIdx.x;
    const int r    = blockIdx.x * 4 + (tid >> 6);
    const int lane = tid & 63;

    float mv[KSPLIT], lv[KSPLIT];
#pragma unroll
    for (int s = 0; s < KSPLIT; ++s) {
        mv[s] = mlb[(r * KSPLIT + s) * 2 + 0];
        lv[s] = mlb[(r * KSPLIT + s) * 2 + 1];
    }
    float M = fmaxf(fmaxf(mv[0], mv[1]), fmaxf(mv[2], mv[3]));
    float coef[KSPLIT];
    float L = 0.f;
#pragma unroll
    for (int s = 0; s < KSPLIT; ++s) {
        coef[s] = __expf(mv[s] - M);
        L = fmaf(lv[s], coef[s], L);
    }
    float rinv = 1.0f / L;

    float4 acc = {0.f, 0.f, 0.f, 0.f};
#pragma unroll
    for (int s = 0; s < KSPLIT; ++s) {
        float4 pv = ((const float4*)(pvb + ((size_t)r * KSPLIT + s) * KCH))[lane];
        float cs = coef[s];
        acc.x = fmaf(cs, pv.x, acc.x);
        acc.y = fmaf(cs, pv.y, acc.y);
        acc.z = fmaf(cs, pv.z, acc.z);
        acc.w = fmaf(cs, pv.w, acc.w);
    }
    acc.x *= rinv; acc.y *= rinv; acc.z *= rinv; acc.w *= rinv;
    *(float4*)(out + (size_t)r * DD + lane * 4) = acc;
}

// ---------------------------------------------------------------------------
extern "C" void kernel_launch(void* const* d_in, const int* in_sizes, int n_in,
                              void* d_out, int out_size, void* d_ws, size_t ws_size,
                              hipStream_t stream) {
    const float* Q   = (const float*)d_in[0];
    const float* K   = (const float*)d_in[1];
    const float* V   = (const float*)d_in[2];
    const int*   vls = (const int*)  d_in[3];
    const float* Wq  = (const float*)d_in[4];
    const float* Wk  = (const float*)d_in[5];
    const float* Wv  = (const float*)d_in[6];
    float* out = (float*)d_out;

    // ws layout: Eq 1 MB | Ek 4 MB | pv 8 MB | ml 64 KB  (total ~13.1 MB)
    float* eq = (float*)d_ws;
    float* ek = eq + (size_t)BB * NQ * HH;
    float* pv = ek + (size_t)BB * NKV * HH;
    float* ml = pv + (size_t)BB * NQ * KSPLIT * KCH;

    proj_exp_kernel<<<(BB*NQ + BB*NKV) / 16, 256, 0, stream>>>(Q, K, Wq, Wk, eq, ek);
    attn_partial_kernel<<<BB * (NQ / 8) * KSPLIT, 512, 0, stream>>>(V, vls, Wv, eq, ek, pv, ml);
    combine_kernel<<<BB * NQ / 4, 256, 0, stream>>>(pv, ml, out);
}

// Round 10
// 144.513 us; speedup vs baseline: 1.5899x; 1.1318x over previous
//
#include <hip/hip_runtime.h>
#include <hip/hip_bf16.h>
#include <math.h>

// Problem constants (fixed by the reference)
#define BB   8
#define NQ   256
#define NKV  1024
#define DD   256   // DQ == DK == DV == 256
#define HH   128   // hidden
#define KSPLIT 4   // k-splits per q-tile (flash-style partial softmax)
#define KCH  256   // k per split (NKV / KSPLIT)
#define NITEMS (BB * (NQ / 8) * KSPLIT)   // 1024 work items
#define NWORK  512                        // persistent worker blocks (2/CU)

typedef float f16v __attribute__((ext_vector_type(16)));

// ---------------------------------------------------------------------------
// Kernel 1: fused projection + exp.  (unchanged from round 6 — measured OK;
// becomes the top dispatch after the attn fix so next round gets its counters)
// ---------------------------------------------------------------------------
__global__ __launch_bounds__(256) void proj_exp_kernel(
    const float* __restrict__ Q, const float* __restrict__ K,
    const float* __restrict__ Wq, const float* __restrict__ Wk,
    float* __restrict__ eqb, float* __restrict__ ekb)
{
    __shared__ __align__(16) float At[32][20];   // [d][row], 16 rows used
    __shared__ __align__(16) float Wt[32][132];  // [d][h], pad to 132

    const int bid = blockIdx.x;
    const bool isQ = bid < (BB * NQ / 16);       // first 128 blocks: Q part
    const float* A = isQ ? Q : K;
    const float* W = isQ ? Wq : Wk;
    float* Out     = isQ ? eqb : ekb;
    const int arow0 = (isQ ? bid : bid - (BB * NQ / 16)) * 16;

    const int tid = threadIdx.x;
    const int rc  = tid >> 5;    // rows rc and rc+8
    const int hc  = tid & 31;    // h-quad: h = hc*4..hc*4+3

    float4 c0 = {0.f,0.f,0.f,0.f}, c1 = c0;

    float4 a4;
    float4 w4[4];

    if (tid < 128)
        a4 = *(const float4*)(A + (size_t)(arow0 + (tid >> 3)) * DD + (tid & 7) * 4);
#pragma unroll
    for (int t = 0; t < 4; ++t) {
        int idx = tid + t * 256;
        int h = idx >> 3, dw = idx & 7;
        w4[t] = *(const float4*)(W + (size_t)h * DD + dw * 4);
    }

    for (int ch = 0; ch < 8; ++ch) {
        __syncthreads();
        if (tid < 128) {
            int r_st = tid >> 3, dq = tid & 7;
            At[dq*4+0][r_st] = a4.x;
            At[dq*4+1][r_st] = a4.y;
            At[dq*4+2][r_st] = a4.z;
            At[dq*4+3][r_st] = a4.w;
        }
#pragma unroll
        for (int t = 0; t < 4; ++t) {
            int idx = tid + t * 256;
            int h = idx >> 3, dw = idx & 7;
            Wt[dw*4+0][h] = w4[t].x;
            Wt[dw*4+1][h] = w4[t].y;
            Wt[dw*4+2][h] = w4[t].z;
            Wt[dw*4+3][h] = w4[t].w;
        }
        __syncthreads();
        if (ch + 1 < 8) {
            const int dc = (ch + 1) * 32;
            if (tid < 128)
                a4 = *(const float4*)(A + (size_t)(arow0 + (tid >> 3)) * DD + dc + (tid & 7) * 4);
#pragma unroll
            for (int t = 0; t < 4; ++t) {
                int idx = tid + t * 256;
                int h = idx >> 3, dw = idx & 7;
                w4[t] = *(const float4*)(W + (size_t)h * DD + dc + dw * 4);
            }
        }
#pragma unroll
        for (int d = 0; d < 32; ++d) {
            float a0  = At[d][rc];
            float a1  = At[d][rc + 8];
            float4 wv = *(const float4*)&Wt[d][hc * 4];
            c0.x = fmaf(a0, wv.x, c0.x); c0.y = fmaf(a0, wv.y, c0.y);
            c0.z = fmaf(a0, wv.z, c0.z); c0.w = fmaf(a0, wv.w, c0.w);
            c1.x = fmaf(a1, wv.x, c1.x); c1.y = fmaf(a1, wv.y, c1.y);
            c1.z = fmaf(a1, wv.z, c1.z); c1.w = fmaf(a1, wv.w, c1.w);
        }
    }

    float4 o;
    float* p0 = Out + (size_t)(arow0 + rc) * HH + hc * 4;
    o.x = __expf(2.f*c0.x); o.y = __expf(2.f*c0.y);
    o.z = __expf(2.f*c0.z); o.w = __expf(2.f*c0.w);
    *(float4*)p0 = o;
    float* p1 = Out + (size_t)(arow0 + rc + 8) * HH + hc * 4;
    o.x = __expf(2.f*c1.x); o.y = __expf(2.f*c1.y);
    o.z = __expf(2.f*c1.z); o.w = __expf(2.f*c1.w);
    *(float4*)p1 = o;
}

// ---------------------------------------------------------------------------
// Kernel 2 v4: PERSISTENT flash-style partial attention.
// NWORK=512 worker blocks (exactly 2/CU) pop items off an atomic queue.
// Item idx -> s = idx>>8 (k-slice), t = idx&255 (q-tile): s=0 (always-active,
// heaviest) items drain first => LPT-style balance; masked items cost one
// atomic + 8 ml stores (pv left unwritten: combine coef is exact 0 and the
// 0xAA ws poison is a finite float, so 0*poison contributes exactly 0).
// Per-item math/structure identical to the round-6-verified kernel.
// ---------------------------------------------------------------------------
__global__ __launch_bounds__(512) void attn_partial_kernel(
    const float* __restrict__ V, const int* __restrict__ vls,
    const float* __restrict__ Wv,
    const float* __restrict__ eqb, const float* __restrict__ ekb,
    float* __restrict__ pvb, float* __restrict__ mlb,
    unsigned int* __restrict__ qcnt)
{
    __shared__ __align__(16) float sc[8][KCH];        // scores then P (8 KB)
    __shared__ __align__(16) float red[4][8][KCH];    // PV partials (32 KB)
    __shared__ int curs;

    const int tid  = threadIdx.x;
    const int w    = tid >> 6;          // wave 0..7
    const int lane = tid & 63;
    const int qg = w & 1;                            // q-group (rows qg*4..+3)
    const int ks = ((w >> 1) << 3) + (lane >> 3);    // 0..31 k-slot
    const int hg = lane & 7;                         // h-group (h = hg*16..+15)

    // Wv slice (item-invariant): nw2[j] = -2*Wv[hg*16+j]; swv = sum of own Wv
    f16v nw2;
    float swv = 0.f;
#pragma unroll
    for (int i = 0; i < 4; ++i) {
        float4 v4 = *(const float4*)(Wv + hg * 16 + i * 4);
        nw2[i*4+0] = -2.f * v4.x; nw2[i*4+1] = -2.f * v4.y;
        nw2[i*4+2] = -2.f * v4.z; nw2[i*4+3] = -2.f * v4.w;
        swv += v4.x + v4.y + v4.z + v4.w;
    }

    for (;;) {
        __syncthreads();    // protects curs AND sc/red reuse across items
        if (tid == 0) curs = (int)atomicAdd(qcnt, 1u);
        __syncthreads();
        const int idx = curs;
        if (idx >= NITEMS) break;          // uniform across block

        const int s  = idx >> 8;           // 0..3, heavy slices first
        const int t  = idx & 255;          // q-tile
        const int b  = t >> 5;
        const int k0 = s << 8;
        const int r0 = t * 8;              // global row base
        const int vl = vls[b];

        if (k0 >= vl) {
            if (tid < 8) {
                mlb[((r0 + tid) * KSPLIT + s) * 2 + 0] = -1e30f;
                mlb[((r0 + tid) * KSPLIT + s) * 2 + 1] = 0.f;
            }
            continue;
        }

        const int kcnt = min(vl - k0, KCH);
        const int nst  = (kcnt + 31) >> 5;

        // Eq rows in registers: 4 rows x 16 h (per item)
        f16v eqr[4];
#pragma unroll
        for (int r = 0; r < 4; ++r) {
            const float4* p = (const float4*)(eqb + (size_t)(r0 + qg*4 + r) * HH + hg * 16);
            float4 x0 = p[0], x1 = p[1], x2 = p[2], x3 = p[3];
            f16v e;
            e[0]=x0.x;e[1]=x0.y;e[2]=x0.z;e[3]=x0.w; e[4]=x1.x;e[5]=x1.y;e[6]=x1.z;e[7]=x1.w;
            e[8]=x2.x;e[9]=x2.y;e[10]=x2.z;e[11]=x2.w; e[12]=x3.x;e[13]=x3.y;e[14]=x3.z;e[15]=x3.w;
            eqr[r] = e;
        }

        const float* ekbase = ekb + ((size_t)(b * NKV) + k0) * HH + hg * 16;

        auto loadEk = [&](f16v& e, int step) {
            const float4* p = (const float4*)(ekbase + (size_t)(step * 32 + ks) * HH);
            float4 x0 = p[0], x1 = p[1], x2 = p[2], x3 = p[3];
            e[0]=x0.x;e[1]=x0.y;e[2]=x0.z;e[3]=x0.w; e[4]=x1.x;e[5]=x1.y;e[6]=x1.z;e[7]=x1.w;
            e[8]=x2.x;e[9]=x2.y;e[10]=x2.z;e[11]=x2.w; e[12]=x3.x;e[13]=x3.y;e[14]=x3.z;e[15]=x3.w;
        };

        auto body = [&](const f16v& e, int step) {
            float a0 = swv, a1 = swv, a2 = swv, a3 = swv;
#pragma unroll
            for (int j = 0; j < 16; ++j) {
                float ej = e[j];
                float t0 = fmaf(eqr[0][j], ej, 1.0f);
                float t1 = fmaf(eqr[1][j], ej, 1.0f);
                float t2 = fmaf(eqr[2][j], ej, 1.0f);
                float t3 = fmaf(eqr[3][j], ej, 1.0f);
                float r0v = __builtin_amdgcn_rcpf(t0);
                float r1v = __builtin_amdgcn_rcpf(t1);
                float r2v = __builtin_amdgcn_rcpf(t2);
                float r3v = __builtin_amdgcn_rcpf(t3);
                float nj = nw2[j];
                a0 = fmaf(nj, r0v, a0);
                a1 = fmaf(nj, r1v, a1);
                a2 = fmaf(nj, r2v, a2);
                a3 = fmaf(nj, r3v, a3);
            }
            a0 += __shfl_xor(a0, 1); a0 += __shfl_xor(a0, 2); a0 += __shfl_xor(a0, 4);
            a1 += __shfl_xor(a1, 1); a1 += __shfl_xor(a1, 2); a1 += __shfl_xor(a1, 4);
            a2 += __shfl_xor(a2, 1); a2 += __shfl_xor(a2, 2); a2 += __shfl_xor(a2, 4);
            a3 += __shfl_xor(a3, 1); a3 += __shfl_xor(a3, 2); a3 += __shfl_xor(a3, 4);
            if (hg == 0) {
                int kk = step * 32 + ks;
                sc[qg*4+0][kk] = a0;
                sc[qg*4+1][kk] = a1;
                sc[qg*4+2][kk] = a2;
                sc[qg*4+3][kk] = a3;
            }
        };

        // ---- score phase (2-deep register double-buffer)
        f16v ekA, ekB;
        loadEk(ekA, 0);
        for (int st = 0; st < nst; st += 2) {
            if (st + 1 < nst) loadEk(ekB, st + 1);
            body(ekA, st);
            if (st + 1 < nst) {
                if (st + 2 < nst) loadEk(ekA, st + 2);
                body(ekB, st + 1);
            }
        }
        __syncthreads();

        // ---- per-slice masked softmax: wave w owns row w
        {
            float m = -1e30f;
            float sv[4];
#pragma unroll
            for (int i = 0; i < 4; ++i) {
                int kk = i * 64 + lane;
                float sval = sc[w][kk];
                sv[i] = sval;
                if (k0 + kk < vl) m = fmaxf(m, sval);
            }
#pragma unroll
            for (int off = 1; off < 64; off <<= 1) m = fmaxf(m, __shfl_xor(m, off));
            float sum = 0.f;
#pragma unroll
            for (int i = 0; i < 4; ++i) {
                int kk = i * 64 + lane;
                float p = (k0 + kk < vl) ? __expf(sv[i] - m) : 0.f;
                sum += p;
                sc[w][kk] = p;
            }
#pragma unroll
            for (int off = 1; off < 64; off <<= 1) sum += __shfl_xor(sum, off);
            if (lane == 0) {
                mlb[((r0 + w) * KSPLIT + s) * 2 + 0] = m;
                mlb[((r0 + w) * KSPLIT + s) * 2 + 1] = sum;
            }
        }
        __syncthreads();

        // ---- PV: wave w owns k in [w*32, w*32+32); accumulates ALL 8 rows
        float4 acc[8];
#pragma unroll
        for (int r = 0; r < 8; ++r) acc[r] = make_float4(0.f, 0.f, 0.f, 0.f);
        {
            const int kbase = w * 32;
            if (kbase < kcnt) {
                const float* vb = V + ((size_t)b * NKV + k0 + kbase) * DD + lane * 4;
                for (int kk = 0; kk < 32; kk += 4) {
                    float4 pr[8];
#pragma unroll
                    for (int r = 0; r < 8; ++r)
                        pr[r] = *(const float4*)&sc[r][kbase + kk];   // wave-uniform
#pragma unroll
                    for (int u = 0; u < 4; ++u) {
                        float4 vv = *(const float4*)(vb + (size_t)(kk + u) * DD);
#pragma unroll
                        for (int r = 0; r < 8; ++r) {
                            float p = (u == 0) ? pr[r].x : (u == 1) ? pr[r].y
                                    : (u == 2) ? pr[r].z : pr[r].w;
                            acc[r].x = fmaf(p, vv.x, acc[r].x);
                            acc[r].y = fmaf(p, vv.y, acc[r].y);
                            acc[r].z = fmaf(p, vv.z, acc[r].z);
                            acc[r].w = fmaf(p, vv.w, acc[r].w);
                        }
                    }
                }
            }
        }
        // 2-stage cross-wave reduction in LDS (4 + 4 waves), then row-store
        if (w < 4) {
#pragma unroll
            for (int r = 0; r < 8; ++r)
                *(float4*)&red[w][r][lane * 4] = acc[r];
        }
        __syncthreads();
        if (w >= 4) {
#pragma unroll
            for (int r = 0; r < 8; ++r) {
                float4 tv = *(const float4*)&red[w - 4][r][lane * 4];
                tv.x += acc[r].x; tv.y += acc[r].y;
                tv.z += acc[r].z; tv.w += acc[r].w;
                *(float4*)&red[w - 4][r][lane * 4] = tv;
            }
        }
        __syncthreads();
        {
            float4 o = {0.f, 0.f, 0.f, 0.f};
#pragma unroll
            for (int ss = 0; ss < 4; ++ss) {
                float4 tv = *(const float4*)&red[ss][w][lane * 4];
                o.x += tv.x; o.y += tv.y; o.z += tv.z; o.w += tv.w;
            }
            ((float4*)(pvb + ((size_t)(r0 + w) * KSPLIT + s) * KCH))[lane] = o;
        }
    }
}

// ---------------------------------------------------------------------------
// Kernel 3: flash merge of KSPLIT partials per q-row.  (unchanged)
// ---------------------------------------------------------------------------
__global__ __launch_bounds__(256) void combine_kernel(
    const float* __restrict__ pvb, const float* __restrict__ mlb,
    float* __restrict__ out)
{
    const int tid  = threadIdx.x;
    const int r    = blockIdx.x * 4 + (tid >> 6);
    const int lane = tid & 63;

    float mv[KSPLIT], lv[KSPLIT];
#pragma unroll
    for (int s = 0; s < KSPLIT; ++s) {
        mv[s] = mlb[(r * KSPLIT + s) * 2 + 0];
        lv[s] = mlb[(r * KSPLIT + s) * 2 + 1];
    }
    float M = fmaxf(fmaxf(mv[0], mv[1]), fmaxf(mv[2], mv[3]));
    float coef[KSPLIT];
    float L = 0.f;
#pragma unroll
    for (int s = 0; s < KSPLIT; ++s) {
        coef[s] = __expf(mv[s] - M);
        L = fmaf(lv[s], coef[s], L);
    }
    float rinv = 1.0f / L;

    float4 acc = {0.f, 0.f, 0.f, 0.f};
#pragma unroll
    for (int s = 0; s < KSPLIT; ++s) {
        float4 pv = ((const float4*)(pvb + ((size_t)r * KSPLIT + s) * KCH))[lane];
        float cs = coef[s];
        acc.x = fmaf(cs, pv.x, acc.x);
        acc.y = fmaf(cs, pv.y, acc.y);
        acc.z = fmaf(cs, pv.z, acc.z);
        acc.w = fmaf(cs, pv.w, acc.w);
    }
    acc.x *= rinv; acc.y *= rinv; acc.z *= rinv; acc.w *= rinv;
    *(float4*)(out + (size_t)r * DD + lane * 4) = acc;
}

// ---------------------------------------------------------------------------
extern "C" void kernel_launch(void* const* d_in, const int* in_sizes, int n_in,
                              void* d_out, int out_size, void* d_ws, size_t ws_size,
                              hipStream_t stream) {
    const float* Q   = (const float*)d_in[0];
    const float* K   = (const float*)d_in[1];
    const float* V   = (const float*)d_in[2];
    const int*   vls = (const int*)  d_in[3];
    const float* Wq  = (const float*)d_in[4];
    const float* Wk  = (const float*)d_in[5];
    const float* Wv  = (const float*)d_in[6];
    float* out = (float*)d_out;

    // ws layout: Eq 1 MB | Ek 4 MB | pv 8 MB | ml 64 KB | queue counter 4 B
    float* eq = (float*)d_ws;
    float* ek = eq + (size_t)BB * NQ * HH;
    float* pv = ek + (size_t)BB * NKV * HH;
    float* ml = pv + (size_t)BB * NQ * KSPLIT * KCH;
    unsigned int* qcnt = (unsigned int*)(ml + (size_t)BB * NQ * KSPLIT * 2);

    hipMemsetAsync(qcnt, 0, sizeof(unsigned int), stream);
    proj_exp_kernel<<<(BB*NQ + BB*NKV) / 16, 256, 0, stream>>>(Q, K, Wq, Wk, eq, ek);
    attn_partial_kernel<<<NWORK, 512, 0, stream>>>(V, vls, Wv, eq, ek, pv, ml, qcnt);
    combine_kernel<<<BB * NQ / 4, 256, 0, stream>>>(pv, ml, out);
}